// Round 2
// baseline (231.535 us; speedup 1.0000x reference)
//
#include <hip/hip_runtime.h>
#include <math.h>

// x [B=256, T=4096, C=32] f32 -> out [B, 64, 64, 32] f32, PAA=64, GADF.
//
// Two-kernel decomposition (R3/R4):
//  K1 gaf_stats: 2048 blocks x 256 thr (8 blk/CU, 32 waves/CU, NO barriers).
//     Block (b, ch) streams a contiguous 64 KB chunk of x (512 timesteps),
//     emitting 8 raw PAA segment sums + per-wave min/max partials into ws.
//     Pure read stream at full occupancy.
//  K2 gaf_outer: 1024 blocks x 256 thr. Block (b, iq) reduces the tiny
//     per-batch partials (L2-hot), builds p/y in LDS, writes its 128 KB
//     output slab sequentially (1 KB/store instr) with NON-TEMPORAL stores
//     (via clang ext_vector_type — HIP float4 is rejected by the builtin).
//
// Rationale: fused kernel showed phase-2 writes ~ fillBuffer rate (6.6 TB/s)
// but phase-1 reads ~2.2 TB/s with 16 lockstepped waves in one block/CU.
// Decoupling removes the barrier lockstep and doubles read-stream occupancy.

#define BB   256
#define TT   4096
#define CC   32
#define PP   64
#define PSTR 33

typedef float f32x4 __attribute__((ext_vector_type(4)));

// workspace layout (floats)
#define SEG_FLOATS  (BB * PP * CC)          // raw segment sums  [b][s][c]  2 MB
#define MM_FLOATS   (BB * 32 * CC)          // min/max partials  [b][k][c]  1 MB each
#define WS_FLOATS   (SEG_FLOATS + 2 * MM_FLOATS)
#define WS_BYTES    (WS_FLOATS * 4)

__device__ __forceinline__ float4 f4min(float4 a, float4 b) {
    return make_float4(fminf(a.x,b.x), fminf(a.y,b.y), fminf(a.z,b.z), fminf(a.w,b.w));
}
__device__ __forceinline__ float4 f4max(float4 a, float4 b) {
    return make_float4(fmaxf(a.x,b.x), fmaxf(a.y,b.y), fmaxf(a.z,b.z), fmaxf(a.w,b.w));
}
__device__ __forceinline__ void f4add(float4& a, float4 v) {
    a.x += v.x; a.y += v.y; a.z += v.z; a.w += v.w;
}
__device__ __forceinline__ float4 shflxor4(float4 v, int m) {
    return make_float4(__shfl_xor(v.x, m), __shfl_xor(v.y, m),
                       __shfl_xor(v.z, m), __shfl_xor(v.w, m));
}
__device__ __forceinline__ void ntstore4(float4* dst, float4 v) {
    f32x4 t; t.x = v.x; t.y = v.y; t.z = v.z; t.w = v.w;
    __builtin_nontemporal_store(t, (f32x4*)dst);
}

// ---------------- K1: streaming stats ----------------
// grid 2048 = B*8, block 256 (4 waves). Block (b, ch): t in [ch*512, ch*512+512).
// Wave w: t in [ch*512 + w*128, +128) = segments ch*8+2w, ch*8+2w+1.
// Load chunk u (1 KB): lane>>3 = t-offset within 8, (lane&7)*4 = channel.
__global__ __launch_bounds__(256, 8) void gaf_stats(const float* __restrict__ x,
                                                    float* __restrict__ ws) {
    const int tid  = threadIdx.x;
    const int lane = tid & 63;
    const int wave = tid >> 6;           // 0..3
    const int cg   = lane & 7;
    const int blk  = blockIdx.x;
    const int b    = blk >> 3;
    const int ch   = blk & 7;

    const float4* base = (const float4*)x + (size_t)b * (TT * CC / 4)
                         + ch * 4096 + wave * 1024 + lane;

    const float FBIG = 3.402823466e+38f;
    float4 mn = make_float4(FBIG, FBIG, FBIG, FBIG);
    float4 mx = make_float4(-FBIG, -FBIG, -FBIG, -FBIG);
    float4 acc0 = make_float4(0.f, 0.f, 0.f, 0.f);
    float4 acc1 = make_float4(0.f, 0.f, 0.f, 0.f);

    float4 buf[8];
    #pragma unroll
    for (int u = 0; u < 8; ++u) buf[u] = base[u * 64];
    #pragma unroll
    for (int u = 0; u < 8; ++u) { mn = f4min(mn, buf[u]); mx = f4max(mx, buf[u]); f4add(acc0, buf[u]); }
    #pragma unroll
    for (int u = 0; u < 8; ++u) buf[u] = base[(8 + u) * 64];
    #pragma unroll
    for (int u = 0; u < 8; ++u) { mn = f4min(mn, buf[u]); mx = f4max(mx, buf[u]); f4add(acc1, buf[u]); }

    // reduce across the 8 t-offsets (lanes sharing cg are stride-8)
    #pragma unroll
    for (int m = 8; m <= 32; m <<= 1) {
        mn = f4min(mn, shflxor4(mn, m));
        mx = f4max(mx, shflxor4(mx, m));
        f4add(acc0, shflxor4(acc0, m));
        f4add(acc1, shflxor4(acc1, m));
    }

    if (lane < 8) {                      // lane == cg
        const int s0 = ch * 8 + wave * 2;
        *(float4*)&ws[(size_t)b * (PP * CC) + s0 * CC + cg * 4]       = acc0;
        *(float4*)&ws[(size_t)b * (PP * CC) + (s0 + 1) * CC + cg * 4] = acc1;
        const int k = ch * 4 + wave;     // 0..31 partial index
        *(float4*)&ws[SEG_FLOATS             + (size_t)b * (32 * CC) + k * CC + cg * 4] = mn;
        *(float4*)&ws[SEG_FLOATS + MM_FLOATS + (size_t)b * (32 * CC) + k * CC + cg * 4] = mx;
    }
}

// ---------------- K2: outer product + store ----------------
// grid 1024 = B*4, block 256 (4 waves). Block (b, iq): i in [iq*16, iq*16+16).
__global__ __launch_bounds__(256, 4) void gaf_outer(const float* __restrict__ ws,
                                                    float* __restrict__ out) {
    __shared__ float sp[PP * PSTR];
    __shared__ float sy[PP * PSTR];
    __shared__ float4 lmn[32];
    __shared__ float4 lmx[32];

    const int tid  = threadIdx.x;
    const int lane = tid & 63;
    const int wave = tid >> 6;           // 0..3
    const int cg   = lane & 7;
    const int blk  = blockIdx.x;
    const int b    = blk >> 2;
    const int i0   = (blk & 3) * 16;

    // A: reduce the 32 min/max partials -> per-wave partial in LDS
    {
        const int k = wave * 8 + (lane >> 3);
        float4 mnk = *(const float4*)&ws[SEG_FLOATS             + (size_t)b * (32 * CC) + k * CC + cg * 4];
        float4 mxk = *(const float4*)&ws[SEG_FLOATS + MM_FLOATS + (size_t)b * (32 * CC) + k * CC + cg * 4];
        #pragma unroll
        for (int m = 8; m <= 32; m <<= 1) {
            mnk = f4min(mnk, shflxor4(mnk, m));
            mxk = f4max(mxk, shflxor4(mxk, m));
        }
        if (lane < 8) { lmn[wave * 8 + cg] = mnk; lmx[wave * 8 + cg] = mxk; }
    }
    __syncthreads();

    // B+C: finalize min/max (broadcast reads), compute p/y into LDS
    {
        const int cq = tid & 7;
        float4 mnf = f4min(f4min(lmn[cq], lmn[8 + cq]), f4min(lmn[16 + cq], lmn[24 + cq]));
        float4 mxf = f4max(f4max(lmx[cq], lmx[8 + cq]), f4max(lmx[16 + cq], lmx[24 + cq]));
        float4 inv;
        inv.x = 1.0f / (mxf.x - mnf.x);  inv.y = 1.0f / (mxf.y - mnf.y);
        inv.z = 1.0f / (mxf.z - mnf.z);  inv.w = 1.0f / (mxf.w - mnf.w);
        const float s64 = 1.0f / 64.0f;
        #pragma unroll
        for (int h = 0; h < 2; ++h) {
            const int s = (tid >> 3) + h * 32;
            float4 sum = *(const float4*)&ws[(size_t)b * (PP * CC) + s * CC + cq * 4];
            float4 p, y;
            p.x = (sum.x * s64 - mnf.x) * inv.x;  p.y = (sum.y * s64 - mnf.y) * inv.y;
            p.z = (sum.z * s64 - mnf.z) * inv.z;  p.w = (sum.w * s64 - mnf.w) * inv.w;
            y.x = sqrtf(fmaxf(1.f - p.x * p.x, 0.f));  y.y = sqrtf(fmaxf(1.f - p.y * p.y, 0.f));
            y.z = sqrtf(fmaxf(1.f - p.z * p.z, 0.f));  y.w = sqrtf(fmaxf(1.f - p.w * p.w, 0.f));
            *(float4*)&sp[s * PSTR + cq * 4] = p;
            *(float4*)&sy[s * PSTR + cq * 4] = y;
        }
    }
    __syncthreads();

    // D: out[b,i,j,c] = y_i*p_j - p_i*y_j ; wave w owns i in [i0+4w, i0+4w+4)
    const int jrow = lane >> 3;
    float4 pj[8], yj[8];
    #pragma unroll
    for (int jc = 0; jc < 8; ++jc) {
        const int j = jc * 8 + jrow;
        pj[jc] = *(const float4*)&sp[j * PSTR + cg * 4];
        yj[jc] = *(const float4*)&sy[j * PSTR + cg * 4];
    }

    float4* ob = (float4*)out + (size_t)b * (PP * PP * CC / 4) + lane;

    #pragma unroll
    for (int ii = 0; ii < 4; ++ii) {
        const int i = i0 + wave * 4 + ii;
        const float4 pi = *(const float4*)&sp[i * PSTR + cg * 4];
        const float4 yi = *(const float4*)&sy[i * PSTR + cg * 4];
        #pragma unroll
        for (int jc = 0; jc < 8; ++jc) {
            float4 r;
            r.x = yi.x * pj[jc].x - pi.x * yj[jc].x;
            r.y = yi.y * pj[jc].y - pi.y * yj[jc].y;
            r.z = yi.z * pj[jc].z - pi.z * yj[jc].z;
            r.w = yi.w * pj[jc].w - pi.w * yj[jc].w;
            ntstore4(&ob[i * 512 + jc * 64], r);
        }
    }
}

// ---------------- fallback: previous fused kernel (used if ws too small) ----------------
__global__ __launch_bounds__(1024, 4) void gaf_fused(const float* __restrict__ x,
                                                     float* __restrict__ out) {
    __shared__ float sp[PP * PSTR];
    __shared__ float sy[PP * PSTR];
    __shared__ float redmin[16 * CC];
    __shared__ float redmax[16 * CC];

    const int tid  = threadIdx.x;
    const int lane = tid & 63;
    const int wave = tid >> 6;
    const int cg   = lane & 7;
    const int b    = blockIdx.x;

    const float4* xw = (const float4*)x + (size_t)b * (TT * CC / 4) + wave * 2048 + lane;

    const float FBIG = 3.402823466e+38f;
    float4 mn = make_float4(FBIG, FBIG, FBIG, FBIG);
    float4 mx = make_float4(-FBIG, -FBIG, -FBIG, -FBIG);
    float4 acc[4];
    #pragma unroll
    for (int g = 0; g < 4; ++g) acc[g] = make_float4(0.f, 0.f, 0.f, 0.f);

    #pragma unroll
    for (int g = 0; g < 4; ++g) {
        float4 buf[8];
        #pragma unroll
        for (int u = 0; u < 8; ++u) buf[u] = xw[(g * 8 + u) * 64];
        #pragma unroll
        for (int u = 0; u < 8; ++u) {
            mn = f4min(mn, buf[u]); mx = f4max(mx, buf[u]); f4add(acc[g], buf[u]);
        }
    }

    #pragma unroll
    for (int m = 8; m <= 32; m <<= 1) {
        mn = f4min(mn, shflxor4(mn, m));
        mx = f4max(mx, shflxor4(mx, m));
        #pragma unroll
        for (int g = 0; g < 4; ++g) f4add(acc[g], shflxor4(acc[g], m));
    }

    if (lane < 8) {
        *(float4*)&redmin[wave * CC + cg * 4] = mn;
        *(float4*)&redmax[wave * CC + cg * 4] = mx;
    }
    __syncthreads();

    float4 gmn = *(const float4*)&redmin[0 * CC + cg * 4];
    float4 gmx = *(const float4*)&redmax[0 * CC + cg * 4];
    #pragma unroll
    for (int w = 1; w < 16; ++w) {
        gmn = f4min(gmn, *(const float4*)&redmin[w * CC + cg * 4]);
        gmx = f4max(gmx, *(const float4*)&redmax[w * CC + cg * 4]);
    }

    float4 inv;
    inv.x = 1.0f / (gmx.x - gmn.x);  inv.y = 1.0f / (gmx.y - gmn.y);
    inv.z = 1.0f / (gmx.z - gmn.z);  inv.w = 1.0f / (gmx.w - gmn.w);
    const float s64 = 1.0f / 64.0f;

    if (lane < 8) {
        #pragma unroll
        for (int g = 0; g < 4; ++g) {
            float4 p, y;
            p.x = (acc[g].x * s64 - gmn.x) * inv.x;  p.y = (acc[g].y * s64 - gmn.y) * inv.y;
            p.z = (acc[g].z * s64 - gmn.z) * inv.z;  p.w = (acc[g].w * s64 - gmn.w) * inv.w;
            y.x = sqrtf(fmaxf(1.f - p.x * p.x, 0.f));  y.y = sqrtf(fmaxf(1.f - p.y * p.y, 0.f));
            y.z = sqrtf(fmaxf(1.f - p.z * p.z, 0.f));  y.w = sqrtf(fmaxf(1.f - p.w * p.w, 0.f));
            const int s = wave * 4 + g;
            *(float4*)&sp[s * PSTR + cg * 4] = p;
            *(float4*)&sy[s * PSTR + cg * 4] = y;
        }
    }
    __syncthreads();

    const int jrow = lane >> 3;
    float4 pj[8], yj[8];
    #pragma unroll
    for (int jc = 0; jc < 8; ++jc) {
        const int j = jc * 8 + jrow;
        pj[jc] = *(const float4*)&sp[j * PSTR + cg * 4];
        yj[jc] = *(const float4*)&sy[j * PSTR + cg * 4];
    }

    float4* ob = (float4*)out + (size_t)b * (PP * PP * CC / 4) + wave * 2048 + lane;

    #pragma unroll
    for (int ii = 0; ii < 4; ++ii) {
        const float4 pi = *(const float4*)&sp[(wave * 4 + ii) * PSTR + cg * 4];
        const float4 yi = *(const float4*)&sy[(wave * 4 + ii) * PSTR + cg * 4];
        #pragma unroll
        for (int jc = 0; jc < 8; ++jc) {
            float4 r;
            r.x = yi.x * pj[jc].x - pi.x * yj[jc].x;
            r.y = yi.y * pj[jc].y - pi.y * yj[jc].y;
            r.z = yi.z * pj[jc].z - pi.z * yj[jc].z;
            r.w = yi.w * pj[jc].w - pi.w * yj[jc].w;
            ob[ii * 512 + jc * 64] = r;
        }
    }
}

extern "C" void kernel_launch(void* const* d_in, const int* in_sizes, int n_in,
                              void* d_out, int out_size, void* d_ws, size_t ws_size,
                              hipStream_t stream) {
    const float* x = (const float*)d_in[0];
    float* out = (float*)d_out;
    if (d_ws != nullptr && ws_size >= (size_t)WS_BYTES) {
        float* ws = (float*)d_ws;
        gaf_stats<<<BB * 8, 256, 0, stream>>>(x, ws);
        gaf_outer<<<BB * 4, 256, 0, stream>>>(ws, out);
    } else {
        gaf_fused<<<BB, 1024, 0, stream>>>(x, out);
    }
}